// Round 11
// baseline (1492.512 us; speedup 1.0000x reference)
//
#include <hip/hip_runtime.h>
#include <cmath>

typedef _Float16 f16;
typedef _Float16 f16x8 __attribute__((ext_vector_type(8)));
typedef _Float16 f16x4 __attribute__((ext_vector_type(4)));
typedef float f32x4 __attribute__((ext_vector_type(4)));

#define EPSF 1e-6f

// ---------------- async global->LDS, 16B per lane ----------------
__device__ __forceinline__ void gload16(const f16* g, const f16* l) {
  __builtin_amdgcn_global_load_lds(
      (__attribute__((address_space(1))) void*)g,
      (__attribute__((address_space(3))) void*)l, 16, 0, 0);
}

// ---------------- fast exact-GELU via A&S 7.1.26 erf (|err| <= 1.5e-7) --------
__device__ __forceinline__ float fast_gelu(float u) {
  const float z = u * 0.70710678118654752f;
  const float az = fabsf(z);
  const float t = __builtin_amdgcn_rcpf(fmaf(0.3275911f, az, 1.0f));
  float p = 1.061405429f;
  p = fmaf(p, t, -1.453152027f);
  p = fmaf(p, t, 1.421413741f);
  p = fmaf(p, t, -0.284496736f);
  p = fmaf(p, t, 0.254829592f);
  p = p * t;
  const float e = __expf(-az * az);
  float er = fmaf(-p, e, 1.0f);      // erf(|z|)
  er = copysignf(er, z);
  return 0.5f * u * (1.0f + er);
}

// ---------------- weight transpose fp32[K,N] -> f16[N,K] ----------------
__global__ void wtr_k(const float* __restrict__ W, f16* __restrict__ WT, int K, int N) {
  __shared__ float t[32][33];
  const int nb = blockIdx.x * 32, kb = blockIdx.y * 32;
  const int tx = threadIdx.x, ty = threadIdx.y;
#pragma unroll
  for (int i = ty; i < 32; i += 8) t[i][tx] = W[(size_t)(kb + i) * N + nb + tx];
  __syncthreads();
#pragma unroll
  for (int i = ty; i < 32; i += 8) WT[(size_t)(nb + i) * K + kb + tx] = (f16)t[tx][i];
}

// ---------------- flat fp32 -> f16 cast ----------------
__global__ void cast_k(const float* __restrict__ W, f16* __restrict__ H) {
  const size_t i = (size_t)blockIdx.x * 256 + threadIdx.x;
  const float4 v = ((const float4*)W)[i];
  f16x4 o;
  o[0] = (f16)v.x; o[1] = (f16)v.y; o[2] = (f16)v.z; o[3] = (f16)v.w;
  ((f16x4*)H)[i] = o;
}

// ---------------- per-(b,sblk,d) partial sum of clipped x^2 ----------------
__global__ void colsq_k(const float* __restrict__ x, float* __restrict__ part) {
  const int d = blockIdx.x * 256 + threadIdx.x;
  const int sb = blockIdx.y;
  const int b = blockIdx.z;
  const float* p = x + ((size_t)b * 4096 + (size_t)sb * 256) * 1024 + d;
  float acc = 0.f;
#pragma unroll 4
  for (int s = 0; s < 256; ++s) {
    float v = p[(size_t)s * 1024];
    v = fminf(fmaxf(v, -10.f), 10.f);
    acc = fmaf(v, v, acc);
  }
  part[((size_t)b * 16 + sb) * 1024 + d] = acc;
}

// ---------------- Gs, Gt -> Gsum, amp per (b,d) ----------------
__global__ void stats_k(const float* __restrict__ part, float* __restrict__ Gsum,
                        float* __restrict__ amp) {
  const int b = blockIdx.x;
  const int t = threadIdx.x;
  __shared__ double red[256];
  float cs[4];
  double tot = 0.0;
#pragma unroll
  for (int i = 0; i < 4; ++i) {
    const int d = t + i * 256;
    double s = 0.0;
    for (int k = 0; k < 16; ++k) s += (double)part[((size_t)b * 16 + k) * 1024 + d];
    cs[i] = (float)s;
    tot += s;
  }
  red[t] = tot;
  __syncthreads();
  for (int st = 128; st > 0; st >>= 1) {
    if (t < st) red[t] += red[t + st];
    __syncthreads();
  }
  const float Gs = fmaxf(sqrtf((float)red[0] + EPSF), EPSF);
#pragma unroll
  for (int i = 0; i < 4; ++i) {
    const int d = t + i * 256;
    const float Gt = fmaxf(sqrtf(cs[i] + EPSF), EPSF);
    const float gs = Gs + Gt;
    Gsum[(b << 10) + d] = gs;
    amp[(b << 10) + d] = sqrtf(gs * gs + EPSF);
  }
}

// ------- rowterm split-K -------
__global__ void rtp_k(const float* __restrict__ amp, const float* __restrict__ Wa,
                      double* __restrict__ part) {
  const int d = blockIdx.x * 256 + threadIdx.x;
  const int b = blockIdx.y;
  const int kc = blockIdx.z;
  const float* a = amp + (b << 10);
  double acc = 0.0;
  for (int jj = 0; jj < 128; ++jj) {
    const int k = kc * 128 + jj;
    acc += (double)a[k] * (double)Wa[((size_t)k << 10) + d];
  }
  part[(((size_t)b * 8 + kc) << 10) + d] = acc;
}
__global__ void rtr_k(const double* __restrict__ part, const float* __restrict__ ba,
                      const float* __restrict__ bp, const float* __restrict__ gbias,
                      float* __restrict__ rt) {
  const int d = blockIdx.x * 256 + threadIdx.x;
  const int b = blockIdx.y;
  double acc = 0.0;
#pragma unroll
  for (int kc = 0; kc < 8; ++kc) acc += part[(((size_t)b * 8 + kc) << 10) + d];
  rt[(b << 10) + d] = (float)acc + ba[d] + bp[d] + gbias[d];
}

// ------- combined-bias split-K -------
__global__ void bcp_k(const float* __restrict__ b2r, const float* __restrict__ b2i,
                      const float* __restrict__ We, double* __restrict__ part) {
  const int n = blockIdx.x * 256 + threadIdx.x;
  const int kc = blockIdx.y;
  double acc = 0.0;
  for (int jj = 0; jj < 128; ++jj) {
    const int j = kc * 128 + jj;
    const float bv = (j < 1024) ? b2r[j] : b2i[j - 1024];
    acc += (double)bv * (double)We[(size_t)j * 1024 + n];
  }
  part[((size_t)kc << 10) + n] = acc;
}
__global__ void bcr_k(const double* __restrict__ part, const float* __restrict__ be,
                      float* __restrict__ bc) {
  const int n = blockIdx.x * 256 + threadIdx.x;
  double acc = 0.0;
#pragma unroll
  for (int kc = 0; kc < 16; ++kc) acc += part[((size_t)kc << 10) + n];
  bc[n] = (float)acc + be[n];
}

// ---------------- ph materialization: two-valued by sign(x) ----------------
__global__ void ph_k(const float* __restrict__ x, f16* __restrict__ ph, float phPos,
                     float phNeg) {
  const size_t i = (size_t)blockIdx.x * 256 + threadIdx.x;
  const float4 v = ((const float4*)x)[i];
  f16x4 o;
  o[0] = (f16)(v.x < 0.f ? phNeg : phPos);
  o[1] = (f16)(v.y < 0.f ? phNeg : phPos);
  o[2] = (f16)(v.z < 0.f ? phNeg : phPos);
  o[3] = (f16)(v.w < 0.f ? phNeg : phPos);
  ((f16x4*)ph)[i] = o;
}

// ---------------- RMSNorm row kernel: f32 in -> f16 out ----------------
__global__ void rms_k(const float* __restrict__ wave, const float* __restrict__ g,
                      f16* __restrict__ o) {
  const size_t row = blockIdx.x;
  const int t = threadIdx.x;
  const float4 v = ((const float4*)(wave + row * 1024))[t];
  float ss = v.x * v.x + v.y * v.y + v.z * v.z + v.w * v.w;
#pragma unroll
  for (int s = 32; s > 0; s >>= 1) ss += __shfl_down(ss, s);
  __shared__ float red[4];
  if ((t & 63) == 0) red[t >> 6] = ss;
  __syncthreads();
  const float tot = red[0] + red[1] + red[2] + red[3];
  const float r = rsqrtf(tot * (1.f / 1024.f) + EPSF);
  const float4 gv = ((const float4*)g)[t];
  f16x4 ov;
  ov[0] = (f16)(v.x * r * gv.x);
  ov[1] = (f16)(v.y * r * gv.y);
  ov[2] = (f16)(v.z * r * gv.z);
  ov[3] = (f16)(v.w * r * gv.w);
  ((f16x4*)(o + row * 1024))[t] = ov;
}

// ======= phased MFMA GEMM: BM=256, BN in {256,128}, BK=32/step, 8 waves =======
// 4-deep LDS ring; stage step s+3 while computing s; 2 phases/step, each:
// {ds_read frags, issue gload_lds, [vmcnt(N) phase1], s_barrier, lgkmcnt(0)+
//  sched_barrier, setprio(1), 16 MFMA, setprio(0), s_barrier}. vmcnt never 0
// in-loop. XOR k-slot swizzle (proven conflict-free), bijective XCD swizzle.
// EPI: 0 = +bias->f32 ; 1 = += ->f32 ; 3 = gelu(+bias)->f16 ; 4 = gate ;
//      5 = plain->f16
template <int EPI, int BN>
__global__ __launch_bounds__(512, 2) void gemm8_k(
    const f16* __restrict__ A, int lda, const f16* __restrict__ BT, int ldb, int K,
    const float* __restrict__ bias, float* __restrict__ outF, f16* __restrict__ outH,
    int ldo, const f16* __restrict__ phm, const float* __restrict__ rowterm,
    const float* __restrict__ Gsum, f16* __restrict__ gr, f16* __restrict__ gi, int r0,
    float ratioNeg, float stNeg) {
  extern __shared__ __align__(16) char smem[];
  f16* sm = (f16*)smem;
  constexpr int NWC = BN / 4;            // per-wave col span (64 / 32)
  constexpr int AN = BN / 64;            // col frags per wave (4 / 2)
  constexpr int NBL = BN / 128;          // B gload lines per step (2 / 1)
  constexpr int BUFE = 8192 + BN * 32;   // ring buffer elems (A 8192 + B)
  constexpr int VMN = 2 * (2 + NBL);     // keep 2 steps in flight (8 / 6)

  const int tid = threadIdx.x;
  const int w = tid >> 6, l = tid & 63;

  // row-outer flatten + bijective XCD-chunk swizzle (m204)
  const int ncol = gridDim.y;
  const int bid = blockIdx.x * ncol + blockIdx.y;
  const int nwg = gridDim.x * ncol;
  const int q = nwg >> 3, rr = nwg & 7;
  const int xcd = bid & 7, idx = bid >> 3;
  const int swz = (xcd < rr ? xcd * (q + 1) : rr * (q + 1) + (xcd - rr) * q) + idx;
  const int bx = swz / ncol, by = swz % ncol;
  const size_t rbase = (size_t)bx * 256;
  const size_t cbase = (size_t)by * BN;

  // staging map: lane covers row srow(+128), 16B slot l&3; global k-slot
  // XOR-pre-swizzled, LDS linear (rule 21)
  const int srow = (w << 4) + (l >> 2);
  const int ss = (((l & 3) ^ ((srow >> 1) & 3)) << 3);
  const f16* gA0 = A + (rbase + srow) * (size_t)lda + ss;
  const f16* gA1 = gA0 + (size_t)128 * lda;
  const f16* gB0 = BT + (cbase + srow) * (size_t)ldb + ss;
  const f16* gB1 = gB0 + (size_t)(NBL == 2 ? 128 : 0) * ldb;

  // read map (verified fragment math: phys = logical ^ ((row>>1)&3))
  const int fr = l & 15, hi = l >> 4;
  const int px = ((hi ^ ((fr >> 1) & 3)) << 3);
  const int wm = w >> 2, wn = w & 3;
  int aoff[2][4], boff[4];
#pragma unroll
  for (int qm = 0; qm < 2; ++qm)
#pragma unroll
    for (int m = 0; m < 4; ++m)
      aoff[qm][m] = (wm * 128 + qm * 64 + m * 16 + fr) * 32 + px;
#pragma unroll
  for (int n = 0; n < AN; ++n) boff[n] = 8192 + (wn * NWC + n * 16 + fr) * 32 + px;

  f32x4 acc[8][AN];
  const f32x4 zero = {0.f, 0.f, 0.f, 0.f};
#pragma unroll
  for (int am = 0; am < 8; ++am)
#pragma unroll
    for (int n = 0; n < AN; ++n) acc[am][n] = zero;

  const int nt = K >> 5;  // K-steps of 32 (all K >= 1024 here, nt >= 32)

  // prologue: stage steps 0,1,2 into ring bufs 0,1,2
#pragma unroll
  for (int s0 = 0; s0 < 3; ++s0) {
    f16* d = sm + s0 * BUFE + (w << 9);
    const size_t kb = (size_t)s0 * 32;
    gload16(gA0 + kb, d);
    gload16(gA1 + kb, d + 4096);
    gload16(gB0 + kb, d + 8192);
    if constexpr (NBL == 2) gload16(gB1 + kb, d + 12288);
  }
  asm volatile("s_waitcnt vmcnt(%0)" ::"n"(VMN) : "memory");
  __builtin_amdgcn_s_barrier();

  for (int s = 0; s < nt; ++s) {
    const int bb = (s & 3) * BUFE;
    const int st = (s + 3 < nt) ? s + 3 : nt - 1;  // clamped tail (dead writes)
    f16* dst = sm + ((s + 3) & 3) * BUFE + (w << 9);
    const size_t kb = (size_t)st * 32;
    // ---- phase 0: rows wm*128 .. +64 ----
    f16x8 af[4], bf[AN];
#pragma unroll
    for (int m = 0; m < 4; ++m) af[m] = *(const f16x8*)(sm + bb + aoff[0][m]);
#pragma unroll
    for (int n = 0; n < AN; ++n) bf[n] = *(const f16x8*)(sm + bb + boff[n]);
    gload16(gA0 + kb, dst);
    gload16(gA1 + kb, dst + 4096);
    __builtin_amdgcn_s_barrier();
    asm volatile("s_waitcnt lgkmcnt(0)" ::: "memory");
    __builtin_amdgcn_sched_barrier(0);
    __builtin_amdgcn_s_setprio(1);
#pragma unroll
    for (int m = 0; m < 4; ++m)
#pragma unroll
      for (int n = 0; n < AN; ++n)
        acc[m][n] = __builtin_amdgcn_mfma_f32_16x16x32_f16(af[m], bf[n], acc[m][n], 0, 0, 0);
    __builtin_amdgcn_s_setprio(0);
    __builtin_amdgcn_s_barrier();
    // ---- phase 1: rows wm*128+64 .. +128 ----
#pragma unroll
    for (int m = 0; m < 4; ++m) af[m] = *(const f16x8*)(sm + bb + aoff[1][m]);
    gload16(gB0 + kb, dst + 8192);
    if constexpr (NBL == 2) gload16(gB1 + kb, dst + 12288);
    asm volatile("s_waitcnt vmcnt(%0)" ::"n"(VMN) : "memory");
    __builtin_amdgcn_s_barrier();
    asm volatile("s_waitcnt lgkmcnt(0)" ::: "memory");
    __builtin_amdgcn_sched_barrier(0);
    __builtin_amdgcn_s_setprio(1);
#pragma unroll
    for (int m = 0; m < 4; ++m)
#pragma unroll
      for (int n = 0; n < AN; ++n)
        acc[4 + m][n] = __builtin_amdgcn_mfma_f32_16x16x32_f16(af[m], bf[n], acc[4 + m][n], 0, 0, 0);
    __builtin_amdgcn_s_setprio(0);
    __builtin_amdgcn_s_barrier();
  }

  // drain DMAs before reusing LDS as epilogue scratch
  asm volatile("s_waitcnt vmcnt(0)" ::: "memory");
  __builtin_amdgcn_s_barrier();

  // epilogue; C/D layout: col = lane&15, row = (lane>>4)*4 + j
  const int r4 = hi << 2;

  if constexpr (EPI == 3 || EPI == 5) {
    float* ep = (float*)(smem + w * 4352);  // wave-private [16][68]
#pragma unroll
    for (int am = 0; am < 8; ++am) {
#pragma unroll
      for (int n = 0; n < AN; ++n) {
        const int cl = n * 16 + fr;
#pragma unroll
        for (int j = 0; j < 4; ++j) {
          float v = acc[am][n][j];
          if constexpr (EPI == 3) v = fast_gelu(v + bias[cbase + wn * NWC + cl]);
          ep[(r4 + j) * 68 + cl] = v;
        }
      }
      asm volatile("s_waitcnt lgkmcnt(0)" ::: "memory");
      __builtin_amdgcn_sched_barrier(0);
#pragma unroll
      for (int it = 0; it < AN / 2; ++it) {  // 16 rows x AN*2 chunks = 64*(AN/2)
        const int rl = l >> 2;
        const int ch = (l & 3) + it * 4;
        const float* pr = &ep[rl * 68 + ch * 8];
        f16x8 o;
#pragma unroll
        for (int e = 0; e < 8; ++e) o[e] = (f16)pr[e];
        *(f16x8*)&outH[(rbase + wm * 128 + am * 16 + rl) * (size_t)ldo +
                       (cbase + wn * NWC + ch * 8)] = o;
      }
      asm volatile("s_waitcnt lgkmcnt(0)" ::: "memory");
      __builtin_amdgcn_sched_barrier(0);
    }
  } else if constexpr (EPI == 4) {
    float* ep = (float*)(smem + w * 4352);
#pragma unroll
    for (int am = 0; am < 8; ++am) {
      float grv[AN][4], giv[AN][4];
#pragma unroll
      for (int n = 0; n < AN; ++n) {
        const size_t col = cbase + wn * NWC + n * 16 + fr;
#pragma unroll
        for (int j = 0; j < 4; ++j) {
          const size_t row = rbase + wm * 128 + am * 16 + r4 + j;
          const int gb = (int)(((size_t)r0 + row) >> 12);  // S = 4096
          const float pre = acc[am][n][j] + rowterm[((size_t)gb << 10) + col];
          const float gate = __builtin_amdgcn_rcpf(1.f + __expf(-pre));
          const float ph = (float)phm[row * 1024 + col];
          const bool neg = ph > 2.f;
          const float gs = Gsum[((size_t)gb << 10) + col];
          grv[n][j] = (neg ? gs * ratioNeg : 0.f) * gate;
          giv[n][j] = gs * (neg ? stNeg : 1.f) * gate;
        }
      }
#pragma unroll
      for (int pass = 0; pass < 2; ++pass) {
        f16* dst = pass ? gi : gr;
#pragma unroll
        for (int n = 0; n < AN; ++n)
#pragma unroll
          for (int j = 0; j < 4; ++j)
            ep[(r4 + j) * 68 + n * 16 + fr] = pass ? giv[n][j] : grv[n][j];
        asm volatile("s_waitcnt lgkmcnt(0)" ::: "memory");
        __builtin_amdgcn_sched_barrier(0);
#pragma unroll
        for (int it = 0; it < AN / 2; ++it) {
          const int rl = l >> 2;
          const int ch = (l & 3) + it * 4;
          const float* pr = &ep[rl * 68 + ch * 8];
          f16x8 o;
#pragma unroll
          for (int e = 0; e < 8; ++e) o[e] = (f16)pr[e];
          *(f16x8*)&dst[(rbase + wm * 128 + am * 16 + rl) * 1024 +
                        (cbase + wn * NWC + ch * 8)] = o;
        }
        asm volatile("s_waitcnt lgkmcnt(0)" ::: "memory");
        __builtin_amdgcn_sched_barrier(0);
      }
    }
  } else {
#pragma unroll
    for (int am = 0; am < 8; ++am) {
#pragma unroll
      for (int n = 0; n < AN; ++n) {
        const size_t col = cbase + wn * NWC + n * 16 + fr;
#pragma unroll
        for (int j = 0; j < 4; ++j) {
          const size_t row = rbase + wm * 128 + am * 16 + r4 + j;
          const float v = acc[am][n][j];
          if constexpr (EPI == 0) {
            outF[row * (size_t)ldo + col] = v + bias[col];
          } else {  // EPI == 1
            outF[row * (size_t)ldo + col] += v;
          }
        }
      }
    }
  }
}

extern "C" void kernel_launch(void* const* d_in, const int* in_sizes, int n_in,
                              void* d_out, int out_size, void* d_ws, size_t ws_size,
                              hipStream_t stream) {
  const float* x     = (const float*)d_in[0];
  const float* Wa    = (const float*)d_in[1];
  const float* ba    = (const float*)d_in[2];
  const float* Wp    = (const float*)d_in[3];
  const float* bp    = (const float*)d_in[4];
  const float* gbias = (const float*)d_in[5];
  const float* w1r   = (const float*)d_in[6];
  const float* b1r   = (const float*)d_in[7];
  const float* w2r   = (const float*)d_in[8];
  const float* b2r   = (const float*)d_in[9];
  const float* w1i   = (const float*)d_in[10];
  const float* b1i   = (const float*)d_in[11];
  const float* w2i   = (const float*)d_in[12];
  const float* b2i   = (const float*)d_in[13];
  const float* We    = (const float*)d_in[14];
  const float* be    = (const float*)d_in[15];
  const float* grms  = (const float*)d_in[16];
  const float* wf1   = (const float*)d_in[17];
  const float* bf1   = (const float*)d_in[18];
  const float* wf2   = (const float*)d_in[19];
  const float* bf2   = (const float*)d_in[20];
  float* out = (float*)d_out;

  // allow >64KB dynamic LDS for the phased GEMM instantiations
  hipFuncSetAttribute((const void*)gemm8_k<3, 256>, hipFuncAttributeMaxDynamicSharedMemorySize, 131072);
  hipFuncSetAttribute((const void*)gemm8_k<5, 256>, hipFuncAttributeMaxDynamicSharedMemorySize, 131072);
  hipFuncSetAttribute((const void*)gemm8_k<4, 128>, hipFuncAttributeMaxDynamicSharedMemorySize, 98304);
  hipFuncSetAttribute((const void*)gemm8_k<0, 128>, hipFuncAttributeMaxDynamicSharedMemorySize, 98304);
  hipFuncSetAttribute((const void*)gemm8_k<1, 128>, hipFuncAttributeMaxDynamicSharedMemorySize, 98304);

  char* ws = (char*)d_ws;
  size_t off = 0;
  auto alloc = [&](size_t bytes) -> void* {
    void* p = (void*)(ws + off);
    off += (bytes + 255) & ~(size_t)255;
    return p;
  };

  // persistent across the whole launch
  f16* WpT   = (f16*)alloc((size_t)1024 * 1024 * 2);
  f16* w1rT  = (f16*)alloc((size_t)4096 * 1024 * 2);
  f16* w1iT  = (f16*)alloc((size_t)4096 * 1024 * 2);
  f16* wf1T  = (f16*)alloc((size_t)2048 * 1024 * 2);
  f16* wf2T  = (f16*)alloc((size_t)1024 * 2048 * 2);
  f16* WcrT  = (f16*)alloc((size_t)1024 * 4096 * 2);  // [n][k] (w2r@We_top)^T
  f16* WciT  = (f16*)alloc((size_t)1024 * 4096 * 2);  // [n][k] (w2i@We_bot)^T
  float* part    = (float*)alloc((size_t)4 * 16 * 1024 * 4);
  float* GsumB   = (float*)alloc((size_t)4 * 1024 * 4);
  float* ampB    = (float*)alloc((size_t)4 * 1024 * 4);
  float* rowterm = (float*)alloc((size_t)4 * 1024 * 4);
  float* bcB     = (float*)alloc((size_t)1024 * 4);
  double* rtPart = (double*)alloc((size_t)4 * 8 * 1024 * 8);
  double* bcPart = (double*)alloc((size_t)16 * 1024 * 8);
  const size_t staticEnd = off;

  // temporaries for the Wc precompute, overlapping the chunk region
  char* tmp = ws + staticEnd;
  f16* WeT  = (f16*)tmp;                                   // [1024][2048], 4 MB
  f16* w2rH = (f16*)(tmp + (size_t)4 * 1024 * 1024);       // f16 cast, 8 MB
  f16* w2iH = (f16*)(tmp + (size_t)12 * 1024 * 1024);      // f16 cast, 8 MB

  {  // weight transposes + f16 casts (grid = (N/32, K/32) for W[K,N])
    dim3 b(32, 8);
    wtr_k<<<dim3(32, 32), b, 0, stream>>>(Wp, WpT, 1024, 1024);
    wtr_k<<<dim3(128, 32), b, 0, stream>>>(w1r, w1rT, 1024, 4096);
    wtr_k<<<dim3(128, 32), b, 0, stream>>>(w1i, w1iT, 1024, 4096);
    wtr_k<<<dim3(64, 32), b, 0, stream>>>(wf1, wf1T, 1024, 2048);
    wtr_k<<<dim3(32, 64), b, 0, stream>>>(wf2, wf2T, 2048, 1024);
    wtr_k<<<dim3(32, 64), b, 0, stream>>>(We, WeT, 2048, 1024);
    cast_k<<<dim3(4096), 256, 0, stream>>>(w2r, w2rH);
    cast_k<<<dim3(4096), 256, 0, stream>>>(w2i, w2iH);
  }

  colsq_k<<<dim3(4, 16, 4), 256, 0, stream>>>(x, part);
  stats_k<<<4, 256, 0, stream>>>(part, GsumB, ampB);
  rtp_k<<<dim3(4, 4, 8), 256, 0, stream>>>(ampB, Wa, rtPart);
  rtr_k<<<dim3(4, 4), 256, 0, stream>>>(rtPart, ba, bp, gbias, rowterm);
  bcp_k<<<dim3(4, 16), 256, 0, stream>>>(b2r, b2i, We, bcPart);
  bcr_k<<<dim3(4), 256, 0, stream>>>(bcPart, be, bcB);

  // WcrT[m][n'] = (w2r@We_top)[n',m] ; WciT[m][n'] = (w2i@We_bot)[n',m]
  gemm8_k<5, 256><<<dim3(4, 16), 512, 131072, stream>>>(WeT, 2048, w2rH, 1024, 1024,
      nullptr, nullptr, WcrT, 4096, nullptr, nullptr, nullptr, nullptr, nullptr, 0, 0.f, 0.f);
  gemm8_k<5, 256><<<dim3(4, 16), 512, 131072, stream>>>(WeT + 1024, 2048, w2iH, 1024, 1024,
      nullptr, nullptr, WciT, 4096, nullptr, nullptr, nullptr, nullptr, nullptr, 0, 0.f, 0.f);

  // wave_repr collapses: ratio = (x<0 ? -0.99 : 0), sqrt_term = (x<0 ? sqrt(1-.99^2) : 1)
  const float ratioNeg = -0.99f;
  const float stNeg = sqrtf(fmaxf(1.0f - 0.99f * 0.99f, EPSF));
  const float phPos = atan2f(1.0f, 0.0f);
  const float phNeg = atan2f(stNeg, ratioNeg);

  const long Ntok = (long)in_sizes[0] / 1024;  // 16384
  // perRow: ph 2K | gr 2K | gi 2K | h1 8K ; waveF overlays ph+gr, outB overlays
  // gi, h2 overlays h1 -> 14336 B/row.
  const size_t perRow = 14336;
  long R = (long)((ws_size > staticEnd ? ws_size - staticEnd : 0) / perRow);
  R &= ~255L;
  if (R > Ntok) R = Ntok;
  if (R < 256) R = 256;

  char* cb = ws + staticEnd;
  f16* phB = (f16*)cb;                               // R x 1024
  f16* grB = (f16*)(cb + (size_t)R * 2048);          // R x 1024
  f16* giB = (f16*)(cb + (size_t)R * 4096);          // R x 1024
  f16* h1B = (f16*)(cb + (size_t)R * 6144);          // R x 4096 (r / i sequentially)
  float* waveF = (float*)phB;                        // R x 1024 f32 (ph+gr dead)
  f16* outB = giB;                                   // R x 1024 (gi dead after up-i)
  f16* h2B = h1B;                                    // R x 2048 (h1 dead after down-i)

  for (long r0 = 0; r0 < Ntok; r0 += R) {
    const long Rc = (Ntok - r0 < R) ? (Ntok - r0) : R;
    const int gm = (int)(Rc / 256);
    ph_k<<<dim3((int)Rc), 256, 0, stream>>>(x + r0 * 1024, phB, phPos, phNeg);
    // gate: pre = ph@Wp + rowterm; gr/gi = (cr/ci)*sigmoid(pre)
    gemm8_k<4, 128><<<dim3(gm, 8), 512, 98304, stream>>>(phB, 1024, WpT, 1024, 1024,
        nullptr, nullptr, nullptr, 1024, phB, rowterm, GsumB, grB, giB, (int)r0,
        ratioNeg, stNeg);
    // real half: up -> gelu -> h1 ; wave = h1 @ WcrT^T + bc
    gemm8_k<3, 256><<<dim3(gm, 16), 512, 131072, stream>>>(grB, 1024, w1rT, 1024, 1024,
        b1r, nullptr, h1B, 4096, nullptr, nullptr, nullptr, nullptr, nullptr, 0, 0.f, 0.f);
    gemm8_k<0, 128><<<dim3(gm, 8), 512, 98304, stream>>>(h1B, 4096, WcrT, 4096, 4096,
        bcB, waveF, nullptr, 1024, nullptr, nullptr, nullptr, nullptr, nullptr, 0, 0.f, 0.f);
    // imag half: up -> gelu -> h1 ; wave += h1 @ WciT^T
    gemm8_k<3, 256><<<dim3(gm, 16), 512, 131072, stream>>>(giB, 1024, w1iT, 1024, 1024,
        b1i, nullptr, h1B, 4096, nullptr, nullptr, nullptr, nullptr, nullptr, 0, 0.f, 0.f);
    gemm8_k<1, 128><<<dim3(gm, 8), 512, 98304, stream>>>(h1B, 4096, WciT, 4096, 4096,
        nullptr, waveF, nullptr, 1024, nullptr, nullptr, nullptr, nullptr, nullptr, 0, 0.f, 0.f);
    rms_k<<<dim3((int)Rc), 256, 0, stream>>>(waveF, grms, outB);
    // block FFN
    gemm8_k<3, 256><<<dim3(gm, 8), 512, 131072, stream>>>(outB, 1024, wf1T, 1024, 1024,
        bf1, nullptr, h2B, 2048, nullptr, nullptr, nullptr, nullptr, nullptr, 0, 0.f, 0.f);
    gemm8_k<0, 128><<<dim3(gm, 8), 512, 98304, stream>>>(h2B, 2048, wf2T, 2048, 2048,
        bf2, out + r0 * 1024, nullptr, 1024, nullptr, nullptr, nullptr, nullptr, nullptr,
        0, 0.f, 0.f);
  }
}

// Round 12
// 1308.086 us; speedup vs baseline: 1.1410x; 1.1410x over previous
//
#include <hip/hip_runtime.h>
#include <cmath>

typedef _Float16 f16;
typedef _Float16 f16x8 __attribute__((ext_vector_type(8)));
typedef _Float16 f16x4 __attribute__((ext_vector_type(4)));
typedef float f32x4 __attribute__((ext_vector_type(4)));

#define EPSF 1e-6f

// ---------------- async global->LDS, 16B per lane ----------------
__device__ __forceinline__ void gload16(const f16* g, const f16* l) {
  __builtin_amdgcn_global_load_lds(
      (__attribute__((address_space(1))) void*)g,
      (__attribute__((address_space(3))) void*)l, 16, 0, 0);
}

// ---------------- fast exact-GELU via A&S 7.1.26 erf (|err| <= 1.5e-7) --------
__device__ __forceinline__ float fast_gelu(float u) {
  const float z = u * 0.70710678118654752f;
  const float az = fabsf(z);
  const float t = __builtin_amdgcn_rcpf(fmaf(0.3275911f, az, 1.0f));
  float p = 1.061405429f;
  p = fmaf(p, t, -1.453152027f);
  p = fmaf(p, t, 1.421413741f);
  p = fmaf(p, t, -0.284496736f);
  p = fmaf(p, t, 0.254829592f);
  p = p * t;
  const float e = __expf(-az * az);
  float er = fmaf(-p, e, 1.0f);      // erf(|z|)
  er = copysignf(er, z);
  return 0.5f * u * (1.0f + er);
}

// ---------------- weight transpose fp32[K,N] -> f16[N,K] ----------------
__global__ void wtr_k(const float* __restrict__ W, f16* __restrict__ WT, int K, int N) {
  __shared__ float t[32][33];
  const int nb = blockIdx.x * 32, kb = blockIdx.y * 32;
  const int tx = threadIdx.x, ty = threadIdx.y;
#pragma unroll
  for (int i = ty; i < 32; i += 8) t[i][tx] = W[(size_t)(kb + i) * N + nb + tx];
  __syncthreads();
#pragma unroll
  for (int i = ty; i < 32; i += 8) WT[(size_t)(nb + i) * K + kb + tx] = (f16)t[tx][i];
}

// ---------------- flat fp32 -> f16 cast ----------------
__global__ void cast_k(const float* __restrict__ W, f16* __restrict__ H) {
  const size_t i = (size_t)blockIdx.x * 256 + threadIdx.x;
  const float4 v = ((const float4*)W)[i];
  f16x4 o;
  o[0] = (f16)v.x; o[1] = (f16)v.y; o[2] = (f16)v.z; o[3] = (f16)v.w;
  ((f16x4*)H)[i] = o;
}

// ---------------- per-(b,sblk,d) partial sum of clipped x^2 ----------------
__global__ void colsq_k(const float* __restrict__ x, float* __restrict__ part) {
  const int d = blockIdx.x * 256 + threadIdx.x;
  const int sb = blockIdx.y;
  const int b = blockIdx.z;
  const float* p = x + ((size_t)b * 4096 + (size_t)sb * 256) * 1024 + d;
  float acc = 0.f;
#pragma unroll 4
  for (int s = 0; s < 256; ++s) {
    float v = p[(size_t)s * 1024];
    v = fminf(fmaxf(v, -10.f), 10.f);
    acc = fmaf(v, v, acc);
  }
  part[((size_t)b * 16 + sb) * 1024 + d] = acc;
}

// ---------------- Gs, Gt -> Gsum, amp per (b,d) ----------------
__global__ void stats_k(const float* __restrict__ part, float* __restrict__ Gsum,
                        float* __restrict__ amp) {
  const int b = blockIdx.x;
  const int t = threadIdx.x;
  __shared__ double red[256];
  float cs[4];
  double tot = 0.0;
#pragma unroll
  for (int i = 0; i < 4; ++i) {
    const int d = t + i * 256;
    double s = 0.0;
    for (int k = 0; k < 16; ++k) s += (double)part[((size_t)b * 16 + k) * 1024 + d];
    cs[i] = (float)s;
    tot += s;
  }
  red[t] = tot;
  __syncthreads();
  for (int st = 128; st > 0; st >>= 1) {
    if (t < st) red[t] += red[t + st];
    __syncthreads();
  }
  const float Gs = fmaxf(sqrtf((float)red[0] + EPSF), EPSF);
#pragma unroll
  for (int i = 0; i < 4; ++i) {
    const int d = t + i * 256;
    const float Gt = fmaxf(sqrtf(cs[i] + EPSF), EPSF);
    const float gs = Gs + Gt;
    Gsum[(b << 10) + d] = gs;
    amp[(b << 10) + d] = sqrtf(gs * gs + EPSF);
  }
}

// ------- rowterm split-K: rtp[b][kc][d] = sum_{k in chunk kc} amp[b,k]*Wa[k,d] -------
__global__ void rtp_k(const float* __restrict__ amp, const float* __restrict__ Wa,
                      double* __restrict__ part) {
  const int d = blockIdx.x * 256 + threadIdx.x;
  const int b = blockIdx.y;
  const int kc = blockIdx.z;
  const float* a = amp + (b << 10);
  double acc = 0.0;
  for (int jj = 0; jj < 128; ++jj) {
    const int k = kc * 128 + jj;
    acc += (double)a[k] * (double)Wa[((size_t)k << 10) + d];
  }
  part[(((size_t)b * 8 + kc) << 10) + d] = acc;
}
__global__ void rtr_k(const double* __restrict__ part, const float* __restrict__ ba,
                      const float* __restrict__ bp, const float* __restrict__ gbias,
                      float* __restrict__ rt) {
  const int d = blockIdx.x * 256 + threadIdx.x;
  const int b = blockIdx.y;
  double acc = 0.0;
#pragma unroll
  for (int kc = 0; kc < 8; ++kc) acc += part[(((size_t)b * 8 + kc) << 10) + d];
  rt[(b << 10) + d] = (float)acc + ba[d] + bp[d] + gbias[d];
}

// ------- combined-bias split-K: bc = b2r@We_top + b2i@We_bot + be -------
__global__ void bcp_k(const float* __restrict__ b2r, const float* __restrict__ b2i,
                      const float* __restrict__ We, double* __restrict__ part) {
  const int n = blockIdx.x * 256 + threadIdx.x;
  const int kc = blockIdx.y;
  double acc = 0.0;
  for (int jj = 0; jj < 128; ++jj) {
    const int j = kc * 128 + jj;
    const float bv = (j < 1024) ? b2r[j] : b2i[j - 1024];
    acc += (double)bv * (double)We[(size_t)j * 1024 + n];
  }
  part[((size_t)kc << 10) + n] = acc;
}
__global__ void bcr_k(const double* __restrict__ part, const float* __restrict__ be,
                      float* __restrict__ bc) {
  const int n = blockIdx.x * 256 + threadIdx.x;
  double acc = 0.0;
#pragma unroll
  for (int kc = 0; kc < 16; ++kc) acc += part[((size_t)kc << 10) + n];
  bc[n] = (float)acc + be[n];
}

// ---------------- ph materialization: two-valued by sign(x) ----------------
__global__ void ph_k(const float* __restrict__ x, f16* __restrict__ ph, float phPos,
                     float phNeg) {
  const size_t i = (size_t)blockIdx.x * 256 + threadIdx.x;
  const float4 v = ((const float4*)x)[i];
  f16x4 o;
  o[0] = (f16)(v.x < 0.f ? phNeg : phPos);
  o[1] = (f16)(v.y < 0.f ? phNeg : phPos);
  o[2] = (f16)(v.z < 0.f ? phNeg : phPos);
  o[3] = (f16)(v.w < 0.f ? phNeg : phPos);
  ((f16x4*)ph)[i] = o;
}

// ---------------- RMSNorm row kernel: f32 in -> f16 out ----------------
__global__ void rms_k(const float* __restrict__ wave, const float* __restrict__ g,
                      f16* __restrict__ o) {
  const size_t row = blockIdx.x;
  const int t = threadIdx.x;
  const float4 v = ((const float4*)(wave + row * 1024))[t];
  float ss = v.x * v.x + v.y * v.y + v.z * v.z + v.w * v.w;
#pragma unroll
  for (int s = 32; s > 0; s >>= 1) ss += __shfl_down(ss, s);
  __shared__ float red[4];
  if ((t & 63) == 0) red[t >> 6] = ss;
  __syncthreads();
  const float tot = red[0] + red[1] + red[2] + red[3];
  const float r = rsqrtf(tot * (1.f / 1024.f) + EPSF);
  const float4 gv = ((const float4*)g)[t];
  f16x4 ov;
  ov[0] = (f16)(v.x * r * gv.x);
  ov[1] = (f16)(v.y * r * gv.y);
  ov[2] = (f16)(v.z * r * gv.z);
  ov[3] = (f16)(v.w * r * gv.w);
  ((f16x4*)(o + row * 1024))[t] = ov;
}

// ======== MFMA GEMM: BM=128 x BN=256, 512 thr / 8 waves (64x64 each) ========
// C[M,N] = A[M,K] * BT[N,K]^T.  2-phase dbuf, gload_lds staging, XOR k-slot
// swizzle (conflict-free, rule 21), row-outer flatten + bijective XCD swizzle.
// f16 epilogues staged through wave-private LDS (stride 65 floats: bank base
// (rl + 8ch) -> 2-way max on reads) -> f16 full-segment stores.
// EPI: 0 = +bias -> f32 ; 1 = += -> f32 ; 3 = gelu(+bias) -> f16 ;
//      4 = gate -> gr,gi f16 ; 5 = plain -> f16
template <int EPI>
__global__ __launch_bounds__(512, 4) void gemm2_k(
    const f16* __restrict__ A, int lda, const f16* __restrict__ BT, int ldb, int K,
    const float* __restrict__ bias, float* __restrict__ outF, f16* __restrict__ outH,
    int ldo, const f16* __restrict__ phm, const float* __restrict__ rowterm,
    const float* __restrict__ Gsum, f16* __restrict__ gr, f16* __restrict__ gi, int r0,
    float ratioNeg, float stNeg) {
  __shared__ __align__(16) char smem[49152];
  f16(*smA)[4096] = reinterpret_cast<f16(*)[4096]>(smem);           // [2][4096]
  f16(*smB)[8192] = reinterpret_cast<f16(*)[8192]>(smem + 16384);   // [2][8192]
  const int tid = threadIdx.x;
  const int w = tid >> 6, l = tid & 63;

  // row-outer flatten + bijective XCD-chunk swizzle (m204)
  const int ncol = gridDim.y;
  const int bid = blockIdx.x * ncol + blockIdx.y;
  const int nwg = gridDim.x * ncol;
  const int q = nwg >> 3, rr = nwg & 7;
  const int xcd = bid & 7, idx = bid >> 3;
  const int swz = (xcd < rr ? xcd * (q + 1) : rr * (q + 1) + (xcd - rr) * q) + idx;
  const int bx = swz / ncol, by = swz % ncol;
  const size_t rbase = (size_t)bx * 128;
  const size_t cbase = (size_t)by * 256;

  const int srow = (w << 4) + (l >> 2);
  const int slot = l & 3;
  const int ss = ((slot ^ ((srow >> 1) & 3)) << 3);

  f32x4 acc[4][4];
  const f32x4 zero = {0.f, 0.f, 0.f, 0.f};
#pragma unroll
  for (int m = 0; m < 4; ++m)
#pragma unroll
    for (int n = 0; n < 4; ++n) acc[m][n] = zero;

  const f16* gA = A + (rbase + srow) * (size_t)lda + ss;
  const f16* gB0 = BT + (cbase + srow) * (size_t)ldb + ss;
  const f16* gB1 = BT + (cbase + srow + 128) * (size_t)ldb + ss;  // +128: same XOR

  const int nk = K >> 5;
  auto stage = [&](int buf, size_t ko) {
    gload16(gA + ko, &smA[buf][w << 9]);
    gload16(gB0 + ko, &smB[buf][w << 9]);
    gload16(gB1 + ko, &smB[buf][4096 + (w << 9)]);
  };
  stage(0, 0);
  __syncthreads();

  const int arow = l & 15;
  const int kg = (((l >> 4) ^ ((arow >> 1) & 3)) << 3);
  const int wr = (w >> 2) << 6;
  const int wc = (w & 3) << 6;

  for (int t = 0; t < nk; ++t) {
    const int cur = t & 1;
    if (t + 1 < nk) stage(cur ^ 1, (size_t)(t + 1) << 5);
    const f16* ap = &smA[cur][(wr + arow) * 32 + kg];
    const f16* bp = &smB[cur][(wc + arow) * 32 + kg];
    f16x8 af[4], bf[4];
#pragma unroll
    for (int m = 0; m < 4; ++m) af[m] = *(const f16x8*)(ap + m * 512);
#pragma unroll
    for (int n = 0; n < 4; ++n) bf[n] = *(const f16x8*)(bp + n * 512);
#pragma unroll
    for (int m = 0; m < 4; ++m)
#pragma unroll
      for (int n = 0; n < 4; ++n)
        acc[m][n] = __builtin_amdgcn_mfma_f32_16x16x32_f16(af[m], bf[n], acc[m][n], 0, 0, 0);
    __syncthreads();
  }

  // epilogue; C/D layout: col = lane&15, row = (lane>>4)*4 + j
  const int fr = l & 15, hi = l >> 4;
  const int r4 = hi << 2;

  if constexpr (EPI == 3 || EPI == 5) {
    // wave-private LDS C-staging ([16][65] floats) -> f16x8 full-segment stores
    float* ep = reinterpret_cast<float*>(smem + w * 4352);
#pragma unroll
    for (int m = 0; m < 4; ++m) {
#pragma unroll
      for (int n = 0; n < 4; ++n) {
        const int cl = n * 16 + fr;
#pragma unroll
        for (int j = 0; j < 4; ++j) {
          float v = acc[m][n][j];
          if constexpr (EPI == 3) v = fast_gelu(v + bias[cbase + wc + cl]);
          ep[(r4 + j) * 65 + cl] = v;
        }
      }
      asm volatile("s_waitcnt lgkmcnt(0)" ::: "memory");
      __builtin_amdgcn_sched_barrier(0);
#pragma unroll
      for (int it = 0; it < 2; ++it) {
        const int rl = l >> 2;
        const int ch = (l & 3) + it * 4;
        const float* pr = &ep[rl * 65 + ch * 8];
        f16x8 o;
#pragma unroll
        for (int e = 0; e < 8; ++e) o[e] = (f16)pr[e];
        *(f16x8*)&outH[(rbase + wr + m * 16 + rl) * (size_t)ldo + (cbase + wc + ch * 8)] = o;
      }
      asm volatile("s_waitcnt lgkmcnt(0)" ::: "memory");
      __builtin_amdgcn_sched_barrier(0);
    }
  } else if constexpr (EPI == 4) {
    // gate epilogue: stage gr then gi per m-block through wave-private LDS
    float* ep = reinterpret_cast<float*>(smem + w * 4352);
#pragma unroll
    for (int m = 0; m < 4; ++m) {
      float grv[4][4], giv[4][4];
#pragma unroll
      for (int n = 0; n < 4; ++n) {
        const size_t col = cbase + wc + n * 16 + fr;
#pragma unroll
        for (int j = 0; j < 4; ++j) {
          const size_t row = rbase + wr + m * 16 + r4 + j;
          const int gb = (int)(((size_t)r0 + row) >> 12);  // S = 4096
          const float pre = acc[m][n][j] + rowterm[((size_t)gb << 10) + col];
          const float gate = __builtin_amdgcn_rcpf(1.f + __expf(-pre));
          const float ph = (float)phm[row * 1024 + col];
          const bool neg = ph > 2.f;
          const float gs = Gsum[((size_t)gb << 10) + col];
          grv[n][j] = (neg ? gs * ratioNeg : 0.f) * gate;
          giv[n][j] = gs * (neg ? stNeg : 1.f) * gate;
        }
      }
#pragma unroll
      for (int pass = 0; pass < 2; ++pass) {
        f16* dst = pass ? gi : gr;
#pragma unroll
        for (int n = 0; n < 4; ++n)
#pragma unroll
          for (int j = 0; j < 4; ++j)
            ep[(r4 + j) * 65 + n * 16 + fr] = pass ? giv[n][j] : grv[n][j];
        asm volatile("s_waitcnt lgkmcnt(0)" ::: "memory");
        __builtin_amdgcn_sched_barrier(0);
#pragma unroll
        for (int it = 0; it < 2; ++it) {  // 16 rows x 8 chunks = 64 lanes x 2
          const int rl = l >> 2;
          const int ch = (l & 3) + it * 4;
          const float* pr = &ep[rl * 65 + ch * 8];
          f16x8 o;
#pragma unroll
          for (int e = 0; e < 8; ++e) o[e] = (f16)pr[e];
          *(f16x8*)&dst[(rbase + wr + m * 16 + rl) * 1024 + (cbase + wc + ch * 8)] = o;
        }
        asm volatile("s_waitcnt lgkmcnt(0)" ::: "memory");
        __builtin_amdgcn_sched_barrier(0);
      }
    }
  } else {
#pragma unroll
    for (int m = 0; m < 4; ++m) {
#pragma unroll
      for (int n = 0; n < 4; ++n) {
        const size_t col = cbase + wc + n * 16 + fr;
#pragma unroll
        for (int j = 0; j < 4; ++j) {
          const size_t row = rbase + wr + m * 16 + r4 + j;
          const float v = acc[m][n][j];
          if constexpr (EPI == 0) {
            outF[row * (size_t)ldo + col] = v + bias[col];
          } else {  // EPI == 1
            outF[row * (size_t)ldo + col] += v;
          }
        }
      }
    }
  }
}

extern "C" void kernel_launch(void* const* d_in, const int* in_sizes, int n_in,
                              void* d_out, int out_size, void* d_ws, size_t ws_size,
                              hipStream_t stream) {
  const float* x     = (const float*)d_in[0];
  const float* Wa    = (const float*)d_in[1];
  const float* ba    = (const float*)d_in[2];
  const float* Wp    = (const float*)d_in[3];
  const float* bp    = (const float*)d_in[4];
  const float* gbias = (const float*)d_in[5];
  const float* w1r   = (const float*)d_in[6];
  const float* b1r   = (const float*)d_in[7];
  const float* w2r   = (const float*)d_in[8];
  const float* b2r   = (const float*)d_in[9];
  const float* w1i   = (const float*)d_in[10];
  const float* b1i   = (const float*)d_in[11];
  const float* w2i   = (const float*)d_in[12];
  const float* b2i   = (const float*)d_in[13];
  const float* We    = (const float*)d_in[14];
  const float* be    = (const float*)d_in[15];
  const float* grms  = (const float*)d_in[16];
  const float* wf1   = (const float*)d_in[17];
  const float* bf1   = (const float*)d_in[18];
  const float* wf2   = (const float*)d_in[19];
  const float* bf2   = (const float*)d_in[20];
  float* out = (float*)d_out;

  char* ws = (char*)d_ws;
  size_t off = 0;
  auto alloc = [&](size_t bytes) -> void* {
    void* p = (void*)(ws + off);
    off += (bytes + 255) & ~(size_t)255;
    return p;
  };

  // persistent across the whole launch
  f16* WpT   = (f16*)alloc((size_t)1024 * 1024 * 2);
  f16* w1rT  = (f16*)alloc((size_t)4096 * 1024 * 2);
  f16* w1iT  = (f16*)alloc((size_t)4096 * 1024 * 2);
  f16* wf1T  = (f16*)alloc((size_t)2048 * 1024 * 2);
  f16* wf2T  = (f16*)alloc((size_t)1024 * 2048 * 2);
  f16* WcrT  = (f16*)alloc((size_t)1024 * 4096 * 2);  // [n][k] (w2r@We_top)^T
  f16* WciT  = (f16*)alloc((size_t)1024 * 4096 * 2);  // [n][k] (w2i@We_bot)^T
  float* part    = (float*)alloc((size_t)4 * 16 * 1024 * 4);
  float* GsumB   = (float*)alloc((size_t)4 * 1024 * 4);
  float* ampB    = (float*)alloc((size_t)4 * 1024 * 4);
  float* rowterm = (float*)alloc((size_t)4 * 1024 * 4);
  float* bcB     = (float*)alloc((size_t)1024 * 4);
  double* rtPart = (double*)alloc((size_t)4 * 8 * 1024 * 8);
  double* bcPart = (double*)alloc((size_t)16 * 1024 * 8);
  const size_t staticEnd = off;

  // temporaries for the Wc precompute, overlapping the chunk region (dead before
  // any chunk kernel writes there; stream ordering guarantees sequencing)
  char* tmp = ws + staticEnd;
  f16* WeT  = (f16*)tmp;                                   // [1024][2048], 4 MB
  f16* w2rH = (f16*)(tmp + (size_t)4 * 1024 * 1024);       // f16 cast, 8 MB
  f16* w2iH = (f16*)(tmp + (size_t)12 * 1024 * 1024);      // f16 cast, 8 MB

  {  // weight transposes + f16 casts (grid = (N/32, K/32) for W[K,N])
    dim3 b(32, 8);
    wtr_k<<<dim3(32, 32), b, 0, stream>>>(Wp, WpT, 1024, 1024);
    wtr_k<<<dim3(128, 32), b, 0, stream>>>(w1r, w1rT, 1024, 4096);
    wtr_k<<<dim3(128, 32), b, 0, stream>>>(w1i, w1iT, 1024, 4096);
    wtr_k<<<dim3(64, 32), b, 0, stream>>>(wf1, wf1T, 1024, 2048);
    wtr_k<<<dim3(32, 64), b, 0, stream>>>(wf2, wf2T, 2048, 1024);
    wtr_k<<<dim3(32, 64), b, 0, stream>>>(We, WeT, 2048, 1024);
    cast_k<<<dim3(4096), 256, 0, stream>>>(w2r, w2rH);
    cast_k<<<dim3(4096), 256, 0, stream>>>(w2i, w2iH);
  }

  colsq_k<<<dim3(4, 16, 4), 256, 0, stream>>>(x, part);
  stats_k<<<4, 256, 0, stream>>>(part, GsumB, ampB);
  rtp_k<<<dim3(4, 4, 8), 256, 0, stream>>>(ampB, Wa, rtPart);
  rtr_k<<<dim3(4, 4), 256, 0, stream>>>(rtPart, ba, bp, gbias, rowterm);
  bcp_k<<<dim3(4, 16), 256, 0, stream>>>(b2r, b2i, We, bcPart);
  bcr_k<<<dim3(4), 256, 0, stream>>>(bcPart, be, bcB);

  // WcrT[m][n'] = (w2r@We_top)[n',m] ; WciT[m][n'] = (w2i@We_bot)[n',m]
  gemm2_k<5><<<dim3(8, 16), 512, 0, stream>>>(WeT, 2048, w2rH, 1024, 1024, nullptr,
      nullptr, WcrT, 4096, nullptr, nullptr, nullptr, nullptr, nullptr, 0, 0.f, 0.f);
  gemm2_k<5><<<dim3(8, 16), 512, 0, stream>>>(WeT + 1024, 2048, w2iH, 1024, 1024, nullptr,
      nullptr, WciT, 4096, nullptr, nullptr, nullptr, nullptr, nullptr, 0, 0.f, 0.f);

  // wave_repr collapses: ratio = (x<0 ? -0.99 : 0), sqrt_term = (x<0 ? sqrt(1-.99^2) : 1)
  const float ratioNeg = -0.99f;
  const float stNeg = sqrtf(fmaxf(1.0f - 0.99f * 0.99f, EPSF));
  const float phPos = atan2f(1.0f, 0.0f);
  const float phNeg = atan2f(stNeg, ratioNeg);

  const long Ntok = (long)in_sizes[0] / 1024;  // 16384
  // perRow: ph 2K | gr 2K | gi 2K | h1 8K ; waveF overlays ph+gr, outB overlays
  // gi, h2 overlays h1 -> 14336 B/row.  No R cap.
  const size_t perRow = 14336;
  long R = (long)((ws_size > staticEnd ? ws_size - staticEnd : 0) / perRow);
  R &= ~255L;
  if (R > Ntok) R = Ntok;
  if (R < 256) R = 256;

  char* cb = ws + staticEnd;
  f16* phB = (f16*)cb;                               // R x 1024
  f16* grB = (f16*)(cb + (size_t)R * 2048);          // R x 1024
  f16* giB = (f16*)(cb + (size_t)R * 4096);          // R x 1024
  f16* h1B = (f16*)(cb + (size_t)R * 6144);          // R x 4096 (r / i sequentially)
  float* waveF = (float*)phB;                        // R x 1024 f32 (ph+gr dead)
  f16* outB = giB;                                   // R x 1024 (gi dead after up-i)
  f16* h2B = h1B;                                    // R x 2048 (h1 dead after down-i)

  for (long r0 = 0; r0 < Ntok; r0 += R) {
    const long Rc = (Ntok - r0 < R) ? (Ntok - r0) : R;
    const int gm = (int)(Rc / 128);
    ph_k<<<dim3((int)Rc), 256, 0, stream>>>(x + r0 * 1024, phB, phPos, phNeg);
    // gate: pre = ph@Wp + rowterm; gr/gi = (cr/ci)*sigmoid(pre)
    gemm2_k<4><<<dim3(gm, 4), 512, 0, stream>>>(phB, 1024, WpT, 1024, 1024, nullptr,
        nullptr, nullptr, 1024, phB, rowterm, GsumB, grB, giB, (int)r0, ratioNeg, stNeg);
    // real half: up -> gelu -> h1 ; wave = h1 @ WcrT^T + bc  (waveF overlays ph+gr)
    gemm2_k<3><<<dim3(gm, 16), 512, 0, stream>>>(grB, 1024, w1rT, 1024, 1024, b1r,
        nullptr, h1B, 4096, nullptr, nullptr, nullptr, nullptr, nullptr, 0, 0.f, 0.f);
    gemm2_k<0><<<dim3(gm, 4), 512, 0, stream>>>(h1B, 4096, WcrT, 4096, 4096, bcB,
        waveF, nullptr, 1024, nullptr, nullptr, nullptr, nullptr, nullptr, 0, 0.f, 0.f);
    // imag half: up -> gelu -> h1 ; wave += h1 @ WciT^T
    gemm2_k<3><<<dim3(gm, 16), 512, 0, stream>>>(giB, 1024, w1iT, 1024, 1024, b1i,
        nullptr, h1B, 4096, nullptr, nullptr, nullptr, nullptr, nullptr, 0, 0.f, 0.f);
    gemm2_k<1><<<dim3(gm, 4), 512, 0, stream>>>(h1B, 4096, WciT, 4096, 4096, nullptr,
        waveF, nullptr, 1024, nullptr, nullptr, nullptr, nullptr, nullptr, 0, 0.f, 0.f);
    rms_k<<<dim3((int)Rc), 256, 0, stream>>>(waveF, grms, outB);
    // block FFN
    gemm2_k<3><<<dim3(gm, 8), 512, 0, stream>>>(outB, 1024, wf1T, 1024, 1024, bf1,
        nullptr, h2B, 2048, nullptr, nullptr, nullptr, nullptr, nullptr, 0, 0.f, 0.f);
    gemm2_k<0><<<dim3(gm, 4), 512, 0, stream>>>(h2B, 2048, wf2T, 2048, 2048, bf2,
        out + r0 * 1024, nullptr, 1024, nullptr, nullptr, nullptr, nullptr, nullptr, 0, 0.f, 0.f);
  }
}